// Round 6
// baseline (135.234 us; speedup 1.0000x reference)
//
#include <hip/hip_runtime.h>
#include <hip/hip_bf16.h>
#include <stdint.h>

// out = (x @ Wv + bv) @ Wo + bo          [all I/O f32]
// Deformable sampling is the identity: |tanh|*2/128 < 0.016 << 0.5 so
// round(samp)==coords; all 7 points sample token n; scores identical;
// softmax exactly uniform; out_h == v. Q/K/offset-MLP are dead code.
// Fused: out = x @ W' + b', W' = Wv@Wo (bf16), b' = bv@Wo + bo (f32).

typedef unsigned short u16;
typedef short bf16x8 __attribute__((ext_vector_type(8)));   // 8 bf16, 4 VGPRs
typedef u16 ushort8 __attribute__((ext_vector_type(8)));
typedef float f32x4 __attribute__((ext_vector_type(4)));

__device__ __forceinline__ u16 f2bf(float f) {
  __hip_bfloat16 h = __float2bfloat16(f);   // hw cvt, RNE
  union { __hip_bfloat16 h; u16 u; } v; v.h = h; return v.u;
}

__device__ __forceinline__ void async_copy16(const void* g, void* lds) {
  __builtin_amdgcn_global_load_lds(
      (const __attribute__((address_space(1))) uint32_t*)g,
      (__attribute__((address_space(3))) uint32_t*)lds, 16, 0, 0);
}

// ws layout: [0, 512K) W'^T bf16 ; [512K, 640K) P bias partials f32 [64][512]
#define WS_WPT 0
#define WS_P   524288

// ---------------------------------------------------------------------------
// blocks 0..63 : W'^T[n'][k'] = sum_m Wo[m][n'] * Wv[k'][m]   (bf16 out)
// blocks 64..127 : bias partials P[j][n] = sum_{m in 8j..8j+7} bv[m]*Wo[m][n]
// ---------------------------------------------------------------------------
__global__ __launch_bounds__(256)
void precompose_fused(const float* __restrict__ Wv, const float* __restrict__ bv,
                      const float* __restrict__ Wo, u16* __restrict__ WpT,
                      float* __restrict__ P) {
  const int b = blockIdx.x;
  const int tid = threadIdx.x;

  if (b >= 64) {              // ---- bias partials (parallel over m-slices)
    const int j = b - 64;
    const int n = tid;
    float s0 = 0.f, s1 = 0.f;
#pragma unroll
    for (int mm = 0; mm < 8; ++mm) {
      const float bvm = bv[8 * j + mm];
      const float* w = Wo + (size_t)(8 * j + mm) * 512;
      s0 += bvm * w[n];
      s1 += bvm * w[n + 256];
    }
    P[(size_t)j * 512 + n] = s0;
    P[(size_t)j * 512 + n + 256] = s1;
    return;
  }

  // ---- W'^T 64x64 tile
  __shared__ u16 As[64 * 72];          // As[n'loc][mloc], stride 72
  __shared__ u16 Bs[64 * 72];          // Bs[k'loc][mloc], stride 72
  const int lane = tid & 63, wave = tid >> 6;
  const int wm = wave & 1, wn = wave >> 1;
  const int q = lane >> 4, lr = lane & 15;
  const int i0 = (b >> 3) * 64;        // n' tile
  const int j0 = (b & 7) * 64;         // k' tile

  f32x4 acc[2][2];
#pragma unroll
  for (int i = 0; i < 2; ++i)
#pragma unroll
    for (int j = 0; j < 2; ++j) { f32x4 z = {0.f,0.f,0.f,0.f}; acc[i][j] = z; }

  for (int m0 = 0; m0 < 512; m0 += 64) {
#pragma unroll
    for (int su = 0; su < 16; ++su) {  // transposed A stage (coalesced reads)
      const int s = su * 256 + tid;
      const int mloc = s >> 6, nloc = s & 63;
      As[nloc * 72 + mloc] = f2bf(Wo[(size_t)(m0 + mloc) * 512 + i0 + nloc]);
    }
#pragma unroll
    for (int su = 0; su < 2; ++su) {   // B stage (vectorized)
      const int s = su * 256 + tid;
      const int row = s >> 3, p = s & 7;
      const float* sv = Wv + (size_t)(j0 + row) * 512 + m0 + p * 8;
      f32x4 a = *(const f32x4*)sv, c4 = *(const f32x4*)(sv + 4);
      ushort8 o;
      o[0]=f2bf(a[0]); o[1]=f2bf(a[1]); o[2]=f2bf(a[2]); o[3]=f2bf(a[3]);
      o[4]=f2bf(c4[0]); o[5]=f2bf(c4[1]); o[6]=f2bf(c4[2]); o[7]=f2bf(c4[3]);
      *(ushort8*)(Bs + row * 72 + p * 8) = o;
    }
    __syncthreads();

#pragma unroll
    for (int kk = 0; kk < 2; ++kk) {
      const int c = kk * 4 + q;
      bf16x8 af[2], bfr[2];
#pragma unroll
      for (int t = 0; t < 2; ++t) {
        af[t]  = *(const bf16x8*)(As + (wm * 32 + t * 16 + lr) * 72 + c * 8);
        bfr[t] = *(const bf16x8*)(Bs + (wn * 32 + t * 16 + lr) * 72 + c * 8);
      }
#pragma unroll
      for (int mt = 0; mt < 2; ++mt)
#pragma unroll
        for (int nt = 0; nt < 2; ++nt)
          acc[mt][nt] = __builtin_amdgcn_mfma_f32_16x16x32_bf16(
              af[mt], bfr[nt], acc[mt][nt], 0, 0, 0);
    }
    __syncthreads();
  }

  // D: col=lane&15, row=quad*4+reg
#pragma unroll
  for (int nt = 0; nt < 2; ++nt) {
    const int col = j0 + wn * 32 + nt * 16 + lr;
#pragma unroll
    for (int mt = 0; mt < 2; ++mt) {
      const int row0 = i0 + wm * 32 + mt * 16 + q * 4;
#pragma unroll
      for (int r = 0; r < 4; ++r)
        WpT[(size_t)(row0 + r) * 512 + col] = f2bf(acc[mt][nt][r]);
    }
  }
}

// ---------------------------------------------------------------------------
// out[M,512] f32 = x[M,512] f32 @ W' (+ b'), W' as BT[n][k] bf16.
// 128x128 tile, BK=64, 4 waves 2x2, 4x4 MFMA tiles/wave.
// Double-buffered LDS, ONE barrier per K-iter:
//   asyncB(k+1)->Bs[alt] ; loadA(k+1)->regs ; compute(cur) ;
//   cvt+storeA(alt) ; __syncthreads ; swap.
// B staged via global_load_lds width=16 (bf16, no cvt); A via regs (f32->bf16).
// grid (128,4): m = blockIdx.x => linear%8 = m-slab%8, all 4 n-blocks of an
// m-slab land on one XCD (x re-reads are L2 hits).
// ---------------------------------------------------------------------------
__global__ __launch_bounds__(256, 2)
void gemm_x_bt(const float* __restrict__ x, const u16* __restrict__ BT,
               const float* __restrict__ P, const float* __restrict__ bo,
               float* __restrict__ C) {
  constexpr int BM = 128, BK = 64;
  __shared__ u16 As[2][BM * BK];
  __shared__ u16 Bs[2][BM * BK];
  __shared__ float bias_s[BM];

  const int tid = threadIdx.x;
  const int lane = tid & 63, wave = tid >> 6;
  const int wm = wave & 1, wn = wave >> 1;
  const int q = lane >> 4, lr = lane & 15;
  const int m0 = blockIdx.x * BM;
  const int n0 = blockIdx.y * BM;

  f32x4 acc[4][4];
#pragma unroll
  for (int i = 0; i < 4; ++i)
#pragma unroll
    for (int j = 0; j < 4; ++j) { f32x4 z = {0.f,0.f,0.f,0.f}; acc[i][j] = z; }

  f32x4 pa0[4], pa1[4];            // prefetched x (f32)

  auto asyncB = [&](int k0, int buf) {
#pragma unroll
    for (int it = 0; it < 4; ++it) {
      const int sbase = it * 256 + wave * 64;      // wave-uniform slot base
      const int s = sbase + lane;
      const int row = s >> 3, p = s & 7;
      const int c = p ^ (row & 7);                 // slot p stores chunk c
      async_copy16(BT + (size_t)(n0 + row) * 512 + k0 + c * 8,
                   &Bs[buf][sbase * 8]);           // + lane*16B implicit
    }
  };
  auto loadA = [&](int k0) {
#pragma unroll
    for (int it = 0; it < 4; ++it) {
      const int s = it * 256 + tid;
      const int row = s >> 3, p = s & 7;
      const int c = p ^ (row & 7);
      const float* sx = x + (size_t)(m0 + row) * 512 + k0 + c * 8;
      pa0[it] = *(const f32x4*)sx;
      pa1[it] = *(const f32x4*)(sx + 4);
    }
  };
  auto storeA = [&](int buf) {
#pragma unroll
    for (int it = 0; it < 4; ++it) {
      const int s = it * 256 + tid;
      ushort8 o;
      o[0]=f2bf(pa0[it][0]); o[1]=f2bf(pa0[it][1]);
      o[2]=f2bf(pa0[it][2]); o[3]=f2bf(pa0[it][3]);
      o[4]=f2bf(pa1[it][0]); o[5]=f2bf(pa1[it][1]);
      o[6]=f2bf(pa1[it][2]); o[7]=f2bf(pa1[it][3]);
      *(ushort8*)(&As[buf][s * 8]) = o;
    }
  };
  auto compute = [&](int buf) {
#pragma unroll
    for (int kk = 0; kk < 2; ++kk) {
      const int c = kk * 4 + q;
      bf16x8 af[4], bfr[4];
#pragma unroll
      for (int t = 0; t < 4; ++t) {
        const int rowA = wm * 64 + t * 16 + lr;
        af[t] = *(const bf16x8*)(&As[buf][rowA * BK + ((c ^ (rowA & 7)) * 8)]);
        const int rowB = wn * 64 + t * 16 + lr;
        bfr[t] = *(const bf16x8*)(&Bs[buf][rowB * BK + ((c ^ (rowB & 7)) * 8)]);
      }
#pragma unroll
      for (int mt = 0; mt < 4; ++mt)
#pragma unroll
        for (int nt = 0; nt < 4; ++nt)
          acc[mt][nt] = __builtin_amdgcn_mfma_f32_16x16x32_bf16(
              af[mt], bfr[nt], acc[mt][nt], 0, 0, 0);
    }
  };

  // prologue: issue tile-0 loads, overlap the bias reduction with them
  asyncB(0, 0);
  loadA(0);
  if (tid < 128) {                 // b' for this block's 128 columns
    float s = bo[n0 + tid];
#pragma unroll 8
    for (int j = 0; j < 64; ++j) s += P[(size_t)j * 512 + n0 + tid];
    bias_s[tid] = s;
  }
  storeA(0);
  __syncthreads();

  int cur = 0;
  for (int k = 1; k < 8; ++k) {
    asyncB(k * 64, cur ^ 1);       // writes to alt: all readers done (barrier)
    loadA(k * 64);
    compute(cur);
    storeA(cur ^ 1);
    __syncthreads();               // drains asyncB+ds_write; flips buffers
    cur ^= 1;
  }
  compute(cur);

  // D: col=lane&15, row=quad*4+reg
#pragma unroll
  for (int nt = 0; nt < 4; ++nt) {
    const int lcol = wn * 64 + nt * 16 + lr;
    const float bsv = bias_s[lcol];
#pragma unroll
    for (int mt = 0; mt < 4; ++mt) {
      const int grow0 = m0 + wm * 64 + mt * 16 + q * 4;
#pragma unroll
      for (int r = 0; r < 4; ++r)
        C[(size_t)(grow0 + r) * 512 + n0 + lcol] = acc[mt][nt][r] + bsv;
    }
  }
}

// ---------------------------------------------------------------------------
extern "C" void kernel_launch(void* const* d_in, const int* in_sizes, int n_in,
                              void* d_out, int out_size, void* d_ws, size_t ws_size,
                              hipStream_t stream) {
  // 0:x 1:H 2:W 3:Wq 4:bq 5:Wk 6:bk 7:Wv 8:bv 9:Wo 10:bo 11..14 offsets(dead)
  const float* x  = (const float*)d_in[0];
  const float* Wv = (const float*)d_in[7];
  const float* bv = (const float*)d_in[8];
  const float* Wo = (const float*)d_in[9];
  const float* bo = (const float*)d_in[10];
  float* outp = (float*)d_out;

  u16*   WpT = (u16*)((uint8_t*)d_ws + WS_WPT);
  float* P   = (float*)((uint8_t*)d_ws + WS_P);

  precompose_fused<<<128, 256, 0, stream>>>(Wv, bv, Wo, WpT, P);
  gemm_x_bt<<<dim3(128, 4), 256, 0, stream>>>(x, WpT, P, bo, outp);
}

// Round 7
// 130.015 us; speedup vs baseline: 1.0401x; 1.0401x over previous
//
#include <hip/hip_runtime.h>
#include <hip/hip_bf16.h>
#include <stdint.h>

// out = (x @ Wv + bv) @ Wo + bo          [all I/O f32]
// Deformable sampling is the identity: |tanh|*2/128 < 0.016 << 0.5 so
// round(samp)==coords; all 7 points sample token n; scores identical;
// softmax exactly uniform; out_h == v. Q/K/offset-MLP are dead code.
// Fused: out = x @ W' + b', W' = Wv@Wo (bf16), b' = bv@Wo + bo (f32).

typedef unsigned short u16;
typedef short bf16x8 __attribute__((ext_vector_type(8)));   // 8 bf16, 4 VGPRs
typedef u16 ushort8 __attribute__((ext_vector_type(8)));
typedef float f32x4 __attribute__((ext_vector_type(4)));

__device__ __forceinline__ u16 f2bf(float f) {
  __hip_bfloat16 h = __float2bfloat16(f);   // hw cvt, RNE
  union { __hip_bfloat16 h; u16 u; } v; v.h = h; return v.u;
}

// ws layout: [0, 512K) W'^T bf16 ; [512K, 640K) P bias partials f32 [64][512]
#define WS_WPT 0
#define WS_P   524288

// ---------------------------------------------------------------------------
// blocks 0..63   : W'^T[n'][k'] = sum_m Wo[m][n'] * Wv[k'][m]   (bf16 out)
// blocks 64..127 : bias partials P[j][n] = sum_{m in 8j..8j+7} bv[m]*Wo[m][n]
// blocks 128..255: prefetch x (warm L2/L3 for the gemm that follows)
// ---------------------------------------------------------------------------
__global__ __launch_bounds__(256)
void precompose_fused(const float* __restrict__ Wv, const float* __restrict__ bv,
                      const float* __restrict__ Wo, const float* __restrict__ x,
                      u16* __restrict__ WpT, float* __restrict__ P) {
  const int b = blockIdx.x;
  const int tid = threadIdx.x;

  if (b >= 128) {             // ---- x prefetch: 128 rows per block
    const int j = b - 128;
    const float* base = x + (size_t)j * 128 * 512;
    f32x4 s = {0.f, 0.f, 0.f, 0.f};
#pragma unroll 8
    for (int it = 0; it < 64; ++it) {
      f32x4 v = *(const f32x4*)(base + (size_t)(it * 256 + tid) * 4);
      s[0] += v[0]; s[1] += v[1]; s[2] += v[2]; s[3] += v[3];
    }
    // data-dependent never-true sink: compiler must keep the loads
    if (s[0] == 1.2345678e30f && s[1] == -s[2] && s[3] == 9.87e21f && tid == 255)
      P[32768 + b] = s[0];
    return;
  }

  if (b >= 64) {              // ---- bias partials (parallel over m-slices)
    const int j = b - 64;
    const int n = tid;
    float s0 = 0.f, s1 = 0.f;
#pragma unroll
    for (int mm = 0; mm < 8; ++mm) {
      const float bvm = bv[8 * j + mm];
      const float* w = Wo + (size_t)(8 * j + mm) * 512;
      s0 += bvm * w[n];
      s1 += bvm * w[n + 256];
    }
    P[(size_t)j * 512 + n] = s0;
    P[(size_t)j * 512 + n + 256] = s1;
    return;
  }

  // ---- W'^T 64x64 tile
  __shared__ u16 As[64 * 72];          // As[n'loc][mloc], stride 72
  __shared__ u16 Bs[64 * 72];          // Bs[k'loc][mloc], stride 72
  const int lane = tid & 63, wave = tid >> 6;
  const int wm = wave & 1, wn = wave >> 1;
  const int q = lane >> 4, lr = lane & 15;
  const int i0 = (b >> 3) * 64;        // n' tile
  const int j0 = (b & 7) * 64;         // k' tile

  f32x4 acc[2][2];
#pragma unroll
  for (int i = 0; i < 2; ++i)
#pragma unroll
    for (int j = 0; j < 2; ++j) { f32x4 z = {0.f,0.f,0.f,0.f}; acc[i][j] = z; }

  for (int m0 = 0; m0 < 512; m0 += 64) {
#pragma unroll
    for (int su = 0; su < 16; ++su) {  // transposed A stage (coalesced reads)
      const int s = su * 256 + tid;
      const int mloc = s >> 6, nloc = s & 63;
      As[nloc * 72 + mloc] = f2bf(Wo[(size_t)(m0 + mloc) * 512 + i0 + nloc]);
    }
#pragma unroll
    for (int su = 0; su < 2; ++su) {   // B stage (vectorized)
      const int s = su * 256 + tid;
      const int row = s >> 3, p = s & 7;
      const float* sv = Wv + (size_t)(j0 + row) * 512 + m0 + p * 8;
      f32x4 a = *(const f32x4*)sv, c4 = *(const f32x4*)(sv + 4);
      ushort8 o;
      o[0]=f2bf(a[0]); o[1]=f2bf(a[1]); o[2]=f2bf(a[2]); o[3]=f2bf(a[3]);
      o[4]=f2bf(c4[0]); o[5]=f2bf(c4[1]); o[6]=f2bf(c4[2]); o[7]=f2bf(c4[3]);
      *(ushort8*)(Bs + row * 72 + p * 8) = o;
    }
    __syncthreads();

#pragma unroll
    for (int kk = 0; kk < 2; ++kk) {
      const int c = kk * 4 + q;
      bf16x8 af[2], bfr[2];
#pragma unroll
      for (int t = 0; t < 2; ++t) {
        af[t]  = *(const bf16x8*)(As + (wm * 32 + t * 16 + lr) * 72 + c * 8);
        bfr[t] = *(const bf16x8*)(Bs + (wn * 32 + t * 16 + lr) * 72 + c * 8);
      }
#pragma unroll
      for (int mt = 0; mt < 2; ++mt)
#pragma unroll
        for (int nt = 0; nt < 2; ++nt)
          acc[mt][nt] = __builtin_amdgcn_mfma_f32_16x16x32_bf16(
              af[mt], bfr[nt], acc[mt][nt], 0, 0, 0);
    }
    __syncthreads();
  }

  // D: col=lane&15, row=quad*4+reg
#pragma unroll
  for (int nt = 0; nt < 2; ++nt) {
    const int col = j0 + wn * 32 + nt * 16 + lr;
#pragma unroll
    for (int mt = 0; mt < 2; ++mt) {
      const int row0 = i0 + wm * 32 + mt * 16 + q * 4;
#pragma unroll
      for (int r = 0; r < 4; ++r)
        WpT[(size_t)(row0 + r) * 512 + col] = f2bf(acc[mt][nt][r]);
    }
  }
}

// ---------------------------------------------------------------------------
// out[M,512] f32 = x[M,512] f32 @ W' (+ b'), W' as BT[n][k] bf16.
// 64x128 tile (BM=64 rows, BN=128 cols), BK=64. Grid 1024 (1-D):
//   m_idx = bid & 255, n_idx = bid >> 8  => the 4 n-blocks of an m-slab are
//   ids {m, m+256, m+512, m+768}: same id%8 => same XCD (x reuse in L2).
// 4 blocks/CU (launch_bounds(256,4), LDS 24.5 KB, VGPR<=128) = 4 waves/SIMD
// for latency hiding. Register prefetch, 2 barriers/iter (R5 structure).
// C written with nontemporal stores (never re-read; keep L2 for x).
// ---------------------------------------------------------------------------
__global__ __launch_bounds__(256, 4)
void gemm_x_bt(const float* __restrict__ x, const u16* __restrict__ BT,
               const float* __restrict__ P, const float* __restrict__ bo,
               float* __restrict__ C) {
  constexpr int BM = 64, BN = 128, BK = 64;
  __shared__ u16 As[BM * BK];          // x-tile bf16, XOR-swizzled chunks
  __shared__ u16 Bs[BN * BK];          // W'^T tile
  __shared__ float bias_s[BN];

  const int tid = threadIdx.x;
  const int lane = tid & 63, wave = tid >> 6;
  const int wm = wave & 1, wn = wave >> 1;
  const int q = lane >> 4, lr = lane & 15;
  const int bid = blockIdx.x;
  const int m0 = (bid & 255) * BM;
  const int n0 = (bid >> 8) * BN;

  f32x4 acc[2][4];
#pragma unroll
  for (int i = 0; i < 2; ++i)
#pragma unroll
    for (int j = 0; j < 4; ++j) { f32x4 z = {0.f,0.f,0.f,0.f}; acc[i][j] = z; }

  f32x4 pa0[2], pa1[2];            // prefetched x (2 slots/thread)
  ushort8 pb[4];                   // prefetched BT (4 slots/thread)

  auto load_tile = [&](int k0) {
#pragma unroll
    for (int it = 0; it < 2; ++it) {           // A: 512 slots
      const int s = it * 256 + tid;
      const int row = s >> 3, p = s & 7;
      const int c = p ^ (row & 7);
      const float* sx = x + (size_t)(m0 + row) * 512 + k0 + c * 8;
      pa0[it] = *(const f32x4*)sx;
      pa1[it] = *(const f32x4*)(sx + 4);
    }
#pragma unroll
    for (int it = 0; it < 4; ++it) {           // B: 1024 slots
      const int s = it * 256 + tid;
      const int row = s >> 3, p = s & 7;
      const int c = p ^ (row & 7);
      pb[it] = *(const ushort8*)(BT + (size_t)(n0 + row) * 512 + k0 + c * 8);
    }
  };
  auto store_tile = [&]() {
#pragma unroll
    for (int it = 0; it < 2; ++it) {
      const int s = it * 256 + tid;
      ushort8 o;
      o[0]=f2bf(pa0[it][0]); o[1]=f2bf(pa0[it][1]);
      o[2]=f2bf(pa0[it][2]); o[3]=f2bf(pa0[it][3]);
      o[4]=f2bf(pa1[it][0]); o[5]=f2bf(pa1[it][1]);
      o[6]=f2bf(pa1[it][2]); o[7]=f2bf(pa1[it][3]);
      *(ushort8*)(As + s * 8) = o;
    }
#pragma unroll
    for (int it = 0; it < 4; ++it) {
      const int s = it * 256 + tid;
      *(ushort8*)(Bs + s * 8) = pb[it];
    }
  };
  auto compute = [&]() {
#pragma unroll
    for (int kk = 0; kk < 2; ++kk) {
      const int c = kk * 4 + q;
      bf16x8 af[2], bfr[4];
#pragma unroll
      for (int t = 0; t < 2; ++t) {
        const int rowA = wm * 32 + t * 16 + lr;
        af[t] = *(const bf16x8*)(As + rowA * BK + (c ^ (rowA & 7)) * 8);
      }
#pragma unroll
      for (int t = 0; t < 4; ++t) {
        const int rowB = wn * 64 + t * 16 + lr;
        bfr[t] = *(const bf16x8*)(Bs + rowB * BK + (c ^ (rowB & 7)) * 8);
      }
#pragma unroll
      for (int mt = 0; mt < 2; ++mt)
#pragma unroll
        for (int nt = 0; nt < 4; ++nt)
          acc[mt][nt] = __builtin_amdgcn_mfma_f32_16x16x32_bf16(
              af[mt], bfr[nt], acc[mt][nt], 0, 0, 0);
    }
  };

  // prologue: issue tile-0 loads; overlap bias reduction with them
  load_tile(0);
  if (tid < BN) {
    float s = bo[n0 + tid];
#pragma unroll 8
    for (int j = 0; j < 64; ++j) s += P[(size_t)j * 512 + n0 + tid];
    bias_s[tid] = s;
  }
  store_tile();
  __syncthreads();

  for (int k = 1; k < 8; ++k) {
    load_tile(k * 64);             // next tile in flight during compute
    compute();
    __syncthreads();               // all waves done reading LDS
    store_tile();
    __syncthreads();
  }
  compute();

  // D: col=lane&15, row=quad*4+reg; nontemporal f32 stores
#pragma unroll
  for (int nt = 0; nt < 4; ++nt) {
    const int lcol = wn * 64 + nt * 16 + lr;
    const float bsv = bias_s[lcol];
#pragma unroll
    for (int mt = 0; mt < 2; ++mt) {
      const int grow0 = m0 + wm * 32 + mt * 16 + q * 4;
#pragma unroll
      for (int r = 0; r < 4; ++r)
        __builtin_nontemporal_store(acc[mt][nt][r] + bsv,
                                    C + (size_t)(grow0 + r) * 512 + n0 + lcol);
    }
  }
}

// ---------------------------------------------------------------------------
extern "C" void kernel_launch(void* const* d_in, const int* in_sizes, int n_in,
                              void* d_out, int out_size, void* d_ws, size_t ws_size,
                              hipStream_t stream) {
  // 0:x 1:H 2:W 3:Wq 4:bq 5:Wk 6:bk 7:Wv 8:bv 9:Wo 10:bo 11..14 offsets(dead)
  const float* x  = (const float*)d_in[0];
  const float* Wv = (const float*)d_in[7];
  const float* bv = (const float*)d_in[8];
  const float* Wo = (const float*)d_in[9];
  const float* bo = (const float*)d_in[10];
  float* outp = (float*)d_out;

  u16*   WpT = (u16*)((uint8_t*)d_ws + WS_WPT);
  float* P   = (float*)((uint8_t*)d_ws + WS_P);

  precompose_fused<<<256, 256, 0, stream>>>(Wv, bv, Wo, x, WpT, P);
  gemm_x_bt<<<1024, 256, 0, stream>>>(x, WpT, P, bo, outp);
}